// Round 1
// 1371.685 us; speedup vs baseline: 1.0159x; 1.0159x over previous
//
#include <hip/hip_runtime.h>
#include <math.h>

#define EPSF 1e-6f
#define STX 100   // row stride for X tiles (96 data cols, pad to 100: 16B-aligned, breaks pow2)
#define STH 132   // row stride for H tiles (128 data cols)

__device__ __forceinline__ float silu_f(float x){ return x * (1.0f/(1.0f + __expf(-x))); }

// ---------------- Qnode = node_attrs @ Wq : [N,64] x [64,512] ----------------
__global__ __launch_bounds__(256) void k_qnode(
    const float* __restrict__ na, const float* __restrict__ Wq,
    float* __restrict__ qn)
{
  __shared__ float At[64*16];
  const int nb = blockIdx.x * 16;
  const int t = threadIdx.x;
  for (int f = t; f < 16*64; f += 256){ int n = f>>6, i = f&63; At[i*16+n] = na[(size_t)(nb+n)*64 + i]; }
  __syncthreads();
  float acc0[16], acc1[16];
#pragma unroll
  for (int n=0;n<16;n++){ acc0[n]=0.f; acc1[n]=0.f; }
  for (int i=0;i<64;i++){
    float w0 = Wq[(size_t)i*512 + t];
    float w1 = Wq[(size_t)i*512 + t + 256];
#pragma unroll
    for (int n=0;n<16;n++){ float a = At[i*16+n]; acc0[n] = fmaf(a,w0,acc0[n]); acc1[n] = fmaf(a,w1,acc1[n]); }
  }
#pragma unroll
  for (int n=0;n<16;n++){
    qn[(size_t)(nb+n)*512 + t]       = acc0[n];
    qn[(size_t)(nb+n)*512 + t + 256] = acc1[n];
  }
}

// ================= CSR build: histogram -> exclusive scan -> scatter =================
__global__ __launch_bounds__(256) void k_hist(
    const int* __restrict__ esrc, int E, int* __restrict__ cnt)
{
  int i = blockIdx.x*256 + threadIdx.x;
  if (i < E) atomicAdd(cnt + esrc[i], 1);
}

// single-block exclusive scan; reads counts from cnt_cur, writes off[0..N] and
// rewrites cnt_cur[i] = off[i] (scatter cursor copy).
__global__ __launch_bounds__(1024) void k_scan(
    int* __restrict__ cnt_cur, int N, int* __restrict__ off)
{
  __shared__ int part[1024];
  const int t = threadIdx.x;
  const int ipt = (N + 1023) >> 10;
  int s = 0;
  for (int k=0;k<ipt;k++){ int i = t*ipt + k; if (i < N) s += cnt_cur[i]; }
  part[t] = s;
  __syncthreads();
  for (int d=1; d<1024; d<<=1){
    int v = (t >= d) ? part[t-d] : 0;
    __syncthreads();
    part[t] += v;
    __syncthreads();
  }
  int run = (t==0) ? 0 : part[t-1];
  for (int k=0;k<ipt;k++){
    int i = t*ipt + k;
    if (i < N){ int c = cnt_cur[i]; off[i] = run; cnt_cur[i] = run; run += c; }
  }
  if (t == 1023) off[N] = part[1023];
}

__global__ __launch_bounds__(256) void k_scatter(
    const int* __restrict__ esrc, int E, int* __restrict__ cur, int* __restrict__ perm)
{
  int i = blockIdx.x*256 + threadIdx.x;
  if (i < E){ int p = atomicAdd(cur + esrc[i], 1); perm[p] = i; }
}

// ---------------- edge kernel 1 (CSR path): env-MLP + K-proj + logits ----------------
// No equiv read, NO global atomics: writes per-edge (el, el*w0, el*w1) as elw[e][ el(32)|a0(32)|a1(32) ].
__global__ __launch_bounds__(256,4) void k_edge1(
    const float* __restrict__ ssi, const float* __restrict__ cond,
    const int* __restrict__ esrc,
    const float* __restrict__ W1, const float* __restrict__ b1,
    const float* __restrict__ W2, const float* __restrict__ Wk,
    const float* __restrict__ qn,
    float* __restrict__ elw)
{
  __shared__ float Xs[32*STX];   // 12.8 KB  [r][ s(64) | cond(32) ]
  __shared__ float Hs[32*STH];   // 16.9 KB
  __shared__ float lg[32*32];    // 4 KB
  __shared__ int src_l[32];      // total ~33.1 KB -> 4 blocks/CU
  const int e0 = blockIdx.x * 32;
  const int t = threadIdx.x;
  const int r0 = (t>>5)*4;

  if (t < 32) src_l[t] = esrc[e0+t];
  for (int f=t; f<512; f+=256){ int r=f>>4, q=(f&15)*4;
    *(float4*)(Xs + r*STX + q) = *(const float4*)(ssi + (size_t)(e0+r)*64 + q); }
  { int f=t; int r=f>>3, q=(f&7)*4;
    *(float4*)(Xs + r*STX + 64 + q) = *(const float4*)(cond + (size_t)(e0+r)*32 + q); }
  __syncthreads();

  // H = silu(X @ W_env1 + b_env1)
  {
    const int c0 = (t&31)*4;
    float acc[4][4] = {};
    for (int i0=0;i0<96;i0+=4){
      float4 wv[4], xv[4];
#pragma unroll
      for (int k=0;k<4;k++) wv[k] = *(const float4*)(W1 + (size_t)(i0+k)*128 + c0);
#pragma unroll
      for (int rr=0;rr<4;rr++) xv[rr] = *(const float4*)(Xs + (r0+rr)*STX + i0);
#pragma unroll
      for (int rr=0;rr<4;rr++){
        const float xs[4] = {xv[rr].x,xv[rr].y,xv[rr].z,xv[rr].w};
#pragma unroll
        for (int k=0;k<4;k++){
          acc[rr][0] = fmaf(xs[k], wv[k].x, acc[rr][0]);
          acc[rr][1] = fmaf(xs[k], wv[k].y, acc[rr][1]);
          acc[rr][2] = fmaf(xs[k], wv[k].z, acc[rr][2]);
          acc[rr][3] = fmaf(xs[k], wv[k].w, acc[rr][3]);
        }
      }
    }
    const float4 bb = *(const float4*)(b1 + c0);
#pragma unroll
    for (int rr=0;rr<4;rr++){
      float4 h;
      h.x = silu_f(acc[rr][0]+bb.x); h.y = silu_f(acc[rr][1]+bb.y);
      h.z = silu_f(acc[rr][2]+bb.z); h.w = silu_f(acc[rr][3]+bb.w);
      *(float4*)(Hs + (r0+rr)*STH + c0) = h;
    }
  }
  __syncthreads();

  // w = H @ W_env2 (regs), then park in wl (aliases Hs after barrier)
  float wacc[4][2] = {};
  {
    const int c0 = (t&31)*2;
    for (int j0=0;j0<128;j0+=4){
      float2 w2[4]; float4 hv[4];
#pragma unroll
      for (int k=0;k<4;k++) w2[k] = *(const float2*)(W2 + (size_t)(j0+k)*64 + c0);
#pragma unroll
      for (int rr=0;rr<4;rr++) hv[rr] = *(const float4*)(Hs + (r0+rr)*STH + j0);
#pragma unroll
      for (int rr=0;rr<4;rr++){
        const float hs[4] = {hv[rr].x,hv[rr].y,hv[rr].z,hv[rr].w};
#pragma unroll
        for (int k=0;k<4;k++){
          wacc[rr][0] = fmaf(hs[k], w2[k].x, wacc[rr][0]);
          wacc[rr][1] = fmaf(hs[k], w2[k].y, wacc[rr][1]);
        }
      }
    }
  }
  __syncthreads();
  float* wl = Hs;  // 32 x 66 row-major
  {
    const int c0 = (t&31)*2;
#pragma unroll
    for (int rr=0;rr<4;rr++)
      *(float2*)(wl + (r0+rr)*66 + c0) = make_float2(wacc[rr][0], wacc[rr][1]);
  }

  // K = s @ Wk ; logits[r][m] = K . Q[src]
  for (int it=0; it<4; it++){
    const int c0k = (t&31)*4 + it*128;
    float acc[4][4] = {};
    for (int i0=0;i0<64;i0+=4){
      float4 wv[4], xv[4];
#pragma unroll
      for (int k=0;k<4;k++) wv[k] = *(const float4*)(Wk + (size_t)(i0+k)*512 + c0k);
#pragma unroll
      for (int rr=0;rr<4;rr++) xv[rr] = *(const float4*)(Xs + (r0+rr)*STX + i0);
#pragma unroll
      for (int rr=0;rr<4;rr++){
        const float xs[4] = {xv[rr].x,xv[rr].y,xv[rr].z,xv[rr].w};
#pragma unroll
        for (int k=0;k<4;k++){
          acc[rr][0] = fmaf(xs[k], wv[k].x, acc[rr][0]);
          acc[rr][1] = fmaf(xs[k], wv[k].y, acc[rr][1]);
          acc[rr][2] = fmaf(xs[k], wv[k].z, acc[rr][2]);
          acc[rr][3] = fmaf(xs[k], wv[k].w, acc[rr][3]);
        }
      }
    }
    const int m = ((t&31)>>2) + it*8;
#pragma unroll
    for (int rr=0;rr<4;rr++){
      const float4 q = *(const float4*)(qn + (size_t)src_l[r0+rr]*512 + c0k);
      float p = acc[rr][0]*q.x + acc[rr][1]*q.y + acc[rr][2]*q.z + acc[rr][3]*q.w;
      p += __shfl_xor(p, 1);
      p += __shfl_xor(p, 2);
      if ((t&3)==0) lg[(r0+rr)*32 + m] = p;
    }
  }
  __syncthreads();

  // exp(clip(logits*INV_SQRTD)); stream (el, el*w0, el*w1) to global (coalesced). No atomics.
  for (int f=t; f<1024; f+=256){
    int r=f>>5, m=f&31;
    float l = lg[f] * 0.25f;
    l = fminf(5.0f, fmaxf(-5.0f, l));
    const float el = __expf(l);
    const size_t b = (size_t)(e0+r)*96;
    elw[b + m]      = el;
    elw[b + 32 + m] = el * wl[r*66 + 2*m];
    elw[b + 64 + m] = el * wl[r*66 + 2*m+1];
  }
}

// ---------------- per-node: CSR segment-sum + attn division + env SO(3) layernorm ----------------
// One block per node; thread t = 4*m + c. Replaces the atomic reduction AND k_dnorm.
__global__ __launch_bounds__(128) void k_env(
    const float* __restrict__ elw, const float* __restrict__ equiv,
    const int* __restrict__ perm, const int* __restrict__ off,
    const float* __restrict__ g_env, float* __restrict__ envn)
{
  __shared__ float red[128];
  __shared__ float inv0s, inv1s;
  const int n = blockIdx.x, t = threadIdx.x;
  const int m = t>>2, c = t&3;
  const int j0 = off[n], j1 = off[n+1];
  float den = 0.f, acc = 0.f;
  for (int j=j0; j<j1; j++){
    const int pe = perm[j];                               // uniform -> scalar load
    const size_t b = (size_t)pe*96;
    const float el = elw[b + m];                          // 4-lane broadcast per addr
    const float a  = elw[b + (c ? 64 : 32) + m];
    const float ev = equiv[((size_t)pe*32 + m)*4 + c];    // 512B coalesced per row
    den += el;
    acc = fmaf(a, ev, acc);
  }
  const float x = (den > 0.f) ? acc/den : 0.f;
  red[t] = x*x;
  __syncthreads();
  if (t < 32){
    float p0 = red[4*t];
    float p1 = red[4*t+1]+red[4*t+2]+red[4*t+3];
#pragma unroll
    for (int k=1;k<32;k<<=1){ p0 += __shfl_xor(p0,k); p1 += __shfl_xor(p1,k); }
    if (t==0){ inv0s = 1.0f/sqrtf(p0*(1.0f/32.0f) + EPSF); inv1s = 1.0f/sqrtf(p1*(1.0f/96.0f) + EPSF); }
  }
  __syncthreads();
  const float g = g_env[m*2 + (c?1:0)];
  envn[(size_t)n*128 + t] = x * (c ? inv1s : inv0s) * g;
}

// ================= fallback path (atomic reduction), used only if ws too small =================
__global__ __launch_bounds__(256,4) void k_edge1_atm(
    const float* __restrict__ ssi, const float* __restrict__ cond,
    const float* __restrict__ equiv, const int* __restrict__ esrc,
    const float* __restrict__ W1, const float* __restrict__ b1,
    const float* __restrict__ W2, const float* __restrict__ Wk,
    const float* __restrict__ qn,
    float* __restrict__ denom, float* __restrict__ num)
{
  __shared__ float Xs[32*STX];
  __shared__ float Hs[32*STH];
  __shared__ float lg[32*32];
  __shared__ int src_l[32];
  const int e0 = blockIdx.x * 32;
  const int t = threadIdx.x;
  const int r0 = (t>>5)*4;

  if (t < 32) src_l[t] = esrc[e0+t];
  for (int f=t; f<512; f+=256){ int r=f>>4, q=(f&15)*4;
    *(float4*)(Xs + r*STX + q) = *(const float4*)(ssi + (size_t)(e0+r)*64 + q); }
  { int f=t; int r=f>>3, q=(f&7)*4;
    *(float4*)(Xs + r*STX + 64 + q) = *(const float4*)(cond + (size_t)(e0+r)*32 + q); }
  __syncthreads();

  {
    const int c0 = (t&31)*4;
    float acc[4][4] = {};
    for (int i0=0;i0<96;i0+=4){
      float4 wv[4], xv[4];
#pragma unroll
      for (int k=0;k<4;k++) wv[k] = *(const float4*)(W1 + (size_t)(i0+k)*128 + c0);
#pragma unroll
      for (int rr=0;rr<4;rr++) xv[rr] = *(const float4*)(Xs + (r0+rr)*STX + i0);
#pragma unroll
      for (int rr=0;rr<4;rr++){
        const float xs[4] = {xv[rr].x,xv[rr].y,xv[rr].z,xv[rr].w};
#pragma unroll
        for (int k=0;k<4;k++){
          acc[rr][0] = fmaf(xs[k], wv[k].x, acc[rr][0]);
          acc[rr][1] = fmaf(xs[k], wv[k].y, acc[rr][1]);
          acc[rr][2] = fmaf(xs[k], wv[k].z, acc[rr][2]);
          acc[rr][3] = fmaf(xs[k], wv[k].w, acc[rr][3]);
        }
      }
    }
    const float4 bb = *(const float4*)(b1 + c0);
#pragma unroll
    for (int rr=0;rr<4;rr++){
      float4 h;
      h.x = silu_f(acc[rr][0]+bb.x); h.y = silu_f(acc[rr][1]+bb.y);
      h.z = silu_f(acc[rr][2]+bb.z); h.w = silu_f(acc[rr][3]+bb.w);
      *(float4*)(Hs + (r0+rr)*STH + c0) = h;
    }
  }
  __syncthreads();

  float wacc[4][2] = {};
  {
    const int c0 = (t&31)*2;
    for (int j0=0;j0<128;j0+=4){
      float2 w2[4]; float4 hv[4];
#pragma unroll
      for (int k=0;k<4;k++) w2[k] = *(const float2*)(W2 + (size_t)(j0+k)*64 + c0);
#pragma unroll
      for (int rr=0;rr<4;rr++) hv[rr] = *(const float4*)(Hs + (r0+rr)*STH + j0);
#pragma unroll
      for (int rr=0;rr<4;rr++){
        const float hs[4] = {hv[rr].x,hv[rr].y,hv[rr].z,hv[rr].w};
#pragma unroll
        for (int k=0;k<4;k++){
          wacc[rr][0] = fmaf(hs[k], w2[k].x, wacc[rr][0]);
          wacc[rr][1] = fmaf(hs[k], w2[k].y, wacc[rr][1]);
        }
      }
    }
  }
  __syncthreads();
  float* wl = Hs;
  {
    const int c0 = (t&31)*2;
#pragma unroll
    for (int rr=0;rr<4;rr++)
      *(float2*)(wl + (r0+rr)*66 + c0) = make_float2(wacc[rr][0], wacc[rr][1]);
  }

  for (int it=0; it<4; it++){
    const int c0k = (t&31)*4 + it*128;
    float acc[4][4] = {};
    for (int i0=0;i0<64;i0+=4){
      float4 wv[4], xv[4];
#pragma unroll
      for (int k=0;k<4;k++) wv[k] = *(const float4*)(Wk + (size_t)(i0+k)*512 + c0k);
#pragma unroll
      for (int rr=0;rr<4;rr++) xv[rr] = *(const float4*)(Xs + (r0+rr)*STX + i0);
#pragma unroll
      for (int rr=0;rr<4;rr++){
        const float xs[4] = {xv[rr].x,xv[rr].y,xv[rr].z,xv[rr].w};
#pragma unroll
        for (int k=0;k<4;k++){
          acc[rr][0] = fmaf(xs[k], wv[k].x, acc[rr][0]);
          acc[rr][1] = fmaf(xs[k], wv[k].y, acc[rr][1]);
          acc[rr][2] = fmaf(xs[k], wv[k].z, acc[rr][2]);
          acc[rr][3] = fmaf(xs[k], wv[k].w, acc[rr][3]);
        }
      }
    }
    const int m = ((t&31)>>2) + it*8;
#pragma unroll
    for (int rr=0;rr<4;rr++){
      const float4 q = *(const float4*)(qn + (size_t)src_l[r0+rr]*512 + c0k);
      float p = acc[rr][0]*q.x + acc[rr][1]*q.y + acc[rr][2]*q.z + acc[rr][3]*q.w;
      p += __shfl_xor(p, 1);
      p += __shfl_xor(p, 2);
      if ((t&3)==0) lg[(r0+rr)*32 + m] = p;
    }
  }
  __syncthreads();

  for (int f=t; f<1024; f+=256){
    int r=f>>5, m=f&31;
    float l = lg[f] * 0.25f;
    l = fminf(5.0f, fmaxf(-5.0f, l));
    float el = __expf(l);
    lg[f] = el;
    atomicAdd(denom + (size_t)src_l[r]*32 + m, el);
  }
  __syncthreads();

  for (int f=t; f<1024; f+=256){
    int r=f>>5, m=f&31;
    const float el = lg[r*32+m];
    const float w0 = wl[r*66 + 2*m]   * el;
    const float w1 = wl[r*66 + 2*m+1] * el;
    const float4 ev = *(const float4*)(equiv + ((size_t)(e0+r)*32 + m)*4);
    float* np = num + (size_t)src_l[r]*128 + 4*m;
    atomicAdd(np+0, w0*ev.x);
    atomicAdd(np+1, w1*ev.y);
    atomicAdd(np+2, w1*ev.z);
    atomicAdd(np+3, w1*ev.w);
  }
}

__global__ __launch_bounds__(128) void k_dnorm(
    float* __restrict__ num, const float* __restrict__ denom,
    const float* __restrict__ g_env)
{
  __shared__ float red[128];
  __shared__ float inv0s, inv1s;
  const int n = blockIdx.x, t = threadIdx.x;
  const int m = t>>2, c = t&3;
  const float d = denom[(size_t)n*32+m];
  const float x = (d > 0.0f) ? num[(size_t)n*128+t]/d : 0.0f;
  red[t] = x*x;
  __syncthreads();
  if (t < 32){
    float p0 = red[4*t];
    float p1 = red[4*t+1]+red[4*t+2]+red[4*t+3];
#pragma unroll
    for (int k=1;k<32;k<<=1){ p0 += __shfl_xor(p0,k); p1 += __shfl_xor(p1,k); }
    if (t==0){ inv0s = 1.0f/sqrtf(p0*(1.0f/32.0f) + EPSF); inv1s = 1.0f/sqrtf(p1*(1.0f/96.0f) + EPSF); }
  }
  __syncthreads();
  const float g = g_env[m*2 + (c?1:0)];
  num[(size_t)n*128+t] = x * (c ? inv1s : inv0s) * g;
}

// ---------------- edge kernel 2: gather env, tp + norms, p-MLP, outputs ----------------
__global__ __launch_bounds__(256,3) void k_edge2(
    const float* __restrict__ ssi, const float* __restrict__ cond,
    const float* __restrict__ equiv, const int* __restrict__ esrc,
    const float* __restrict__ envn, const float* __restrict__ g_tp,
    const float* __restrict__ Wp1, const float* __restrict__ bp1,
    const float* __restrict__ Wp2, const float* __restrict__ ruc,
    float* __restrict__ outs, float* __restrict__ oute)
{
  __shared__ float envl[32*STH];   // 16.9 KB gathered env rows (stride 132 kills 16-bank aliasing)
  __shared__ float Xp[32*STX];     // 12.8 KB [r][ tpn(64) | cond(32) ]
  __shared__ float Hp[32*STH];     // 16.9 KB
  __shared__ float inv_l[32*4];
  __shared__ int src_l[32];        // total ~47 KB -> 3 blocks/CU
  const int e0 = blockIdx.x * 32;
  const int t = threadIdx.x;
  const int r0 = (t>>5)*4;
  if (t < 32) src_l[t] = esrc[e0+t];
  __syncthreads();
  for (int f=t; f<1024; f+=256){ int r=f>>5, q=(f&31)*4;
    *(float4*)(envl + r*STH + q) = *(const float4*)(envn + (size_t)src_l[r]*128 + q); }
  { int f=t; int r=f>>3, q=(f&7)*4;
    *(float4*)(Xp + r*STX + 64 + q) = *(const float4*)(cond + (size_t)(e0+r)*32 + q); }
  __syncthreads();

  // 4 per-edge RMS norms of the tensor product (tp never materialized)
  {
    const int r = t>>3, sub = t&7;
    float ss0=0,ss1=0,ss2=0,ss3=0;
#pragma unroll
    for (int mm=0;mm<4;mm++){
      const int m = sub*4+mm;
      const float4 e4 = *(const float4*)(equiv + ((size_t)(e0+r)*32 + m)*4);
      const float4 n4 = *(const float4*)(envl + r*STH + 4*m);
      const float tp0 = e4.x*n4.x;
      const float dv  = e4.y*n4.y + e4.z*n4.z + e4.w*n4.w;
      const float tp1 = dv*0.5773502691896258f;
      ss0 += tp0*tp0;
      ss1 += tp1*tp1;
      ss2 += e4.x*e4.x*(n4.y*n4.y + n4.z*n4.z + n4.w*n4.w);
      ss3 += n4.x*n4.x*(e4.y*e4.y + e4.z*e4.z + e4.w*e4.w);
    }
#pragma unroll
    for (int k=1;k<8;k<<=1){
      ss0 += __shfl_xor(ss0,k); ss1 += __shfl_xor(ss1,k);
      ss2 += __shfl_xor(ss2,k); ss3 += __shfl_xor(ss3,k);
    }
    if (sub == 0){
      inv_l[r*4+0] = 1.0f/sqrtf(ss0*(1.0f/32.0f) + EPSF);
      inv_l[r*4+1] = 1.0f/sqrtf(ss1*(1.0f/32.0f) + EPSF);
      inv_l[r*4+2] = 1.0f/sqrtf(ss2*(1.0f/96.0f) + EPSF);
      inv_l[r*4+3] = 1.0f/sqrtf(ss3*(1.0f/96.0f) + EPSF);
    }
  }
  __syncthreads();

  // Xp scalar cols: xp[2m]=tpn0, xp[2m+1]=tpn1
  for (int f=t; f<2048; f+=256){
    const int r = f>>6, col = f&63, m = col>>1;
    const float4 e4 = *(const float4*)(equiv + ((size_t)(e0+r)*32 + m)*4);
    const float4 n4 = *(const float4*)(envl + r*STH + 4*m);
    float v;
    if (col & 1)
      v = (e4.y*n4.y + e4.z*n4.z + e4.w*n4.w)*0.5773502691896258f * inv_l[r*4+1] * g_tp[m*4+1];
    else
      v = e4.x*n4.x * inv_l[r*4+0] * g_tp[m*4+0];
    Xp[r*STX + col] = v;
  }
  __syncthreads();

  // Hp = silu(Xp @ Wp1 + bp1)
  {
    const int c0 = (t&31)*4;
    float acc[4][4] = {};
    for (int i0=0;i0<96;i0+=4){
      float4 wv[4], xv[4];
#pragma unroll
      for (int k=0;k<4;k++) wv[k] = *(const float4*)(Wp1 + (size_t)(i0+k)*128 + c0);
#pragma unroll
      for (int rr=0;rr<4;rr++) xv[rr] = *(const float4*)(Xp + (r0+rr)*STX + i0);
#pragma unroll
      for (int rr=0;rr<4;rr++){
        const float xs[4] = {xv[rr].x,xv[rr].y,xv[rr].z,xv[rr].w};
#pragma unroll
        for (int k=0;k<4;k++){
          acc[rr][0] = fmaf(xs[k], wv[k].x, acc[rr][0]);
          acc[rr][1] = fmaf(xs[k], wv[k].y, acc[rr][1]);
          acc[rr][2] = fmaf(xs[k], wv[k].z, acc[rr][2]);
          acc[rr][3] = fmaf(xs[k], wv[k].w, acc[rr][3]);
        }
      }
    }
    const float4 bb = *(const float4*)(bp1 + c0);
#pragma unroll
    for (int rr=0;rr<4;rr++){
      float4 h;
      h.x = silu_f(acc[rr][0]+bb.x); h.y = silu_f(acc[rr][1]+bb.y);
      h.z = silu_f(acc[rr][2]+bb.z); h.w = silu_f(acc[rr][3]+bb.w);
      *(float4*)(Hp + (r0+rr)*STH + c0) = h;
    }
  }
  __syncthreads();

  const float rv = ruc[0];
  const float c_old = 1.0f/sqrtf(rv*rv + 1.0f);
  const float c_new = rv * c_old;

  // op[:, :64] = new_scalar -> scalar_out with residual
  {
    const int c0 = (t&31)*2;
    float acc[4][2] = {};
    for (int j0=0;j0<128;j0+=4){
      float2 w2[4]; float4 hv[4];
#pragma unroll
      for (int k=0;k<4;k++) w2[k] = *(const float2*)(Wp2 + (size_t)(j0+k)*192 + c0);
#pragma unroll
      for (int rr=0;rr<4;rr++) hv[rr] = *(const float4*)(Hp + (r0+rr)*STH + j0);
#pragma unroll
      for (int rr=0;rr<4;rr++){
        const float hs[4] = {hv[rr].x,hv[rr].y,hv[rr].z,hv[rr].w};
#pragma unroll
        for (int k=0;k<4;k++){
          acc[rr][0] = fmaf(hs[k], w2[k].x, acc[rr][0]);
          acc[rr][1] = fmaf(hs[k], w2[k].y, acc[rr][1]);
        }
      }
    }
#pragma unroll
    for (int rr=0;rr<4;rr++){
      const size_t e = (size_t)(e0+r0+rr);
      const float2 s2 = *(const float2*)(ssi + e*64 + c0);
      float2 o2; o2.x = c_old*s2.x + c_new*acc[rr][0]; o2.y = c_old*s2.y + c_new*acc[rr][1];
      *(float2*)(outs + e*64 + c0) = o2;
    }
  }

  // op[:, 64:] = pw[m][0..3] -> equiv_out with residual (thread owns mul m = t&31)
  {
    const int m = t&31;
    float acc[4][4] = {};
    for (int j0=0;j0<128;j0+=4){
      float4 w4[4]; float4 hv[4];
#pragma unroll
      for (int k=0;k<4;k++) w4[k] = *(const float4*)(Wp2 + (size_t)(j0+k)*192 + 64 + 4*m);
#pragma unroll
      for (int rr=0;rr<4;rr++) hv[rr] = *(const float4*)(Hp + (r0+rr)*STH + j0);
#pragma unroll
      for (int rr=0;rr<4;rr++){
        const float hs[4] = {hv[rr].x,hv[rr].y,hv[rr].z,hv[rr].w};
#pragma unroll
        for (int k=0;k<4;k++){
          acc[rr][0] = fmaf(hs[k], w4[k].x, acc[rr][0]);
          acc[rr][1] = fmaf(hs[k], w4[k].y, acc[rr][1]);
          acc[rr][2] = fmaf(hs[k], w4[k].z, acc[rr][2]);
          acc[rr][3] = fmaf(hs[k], w4[k].w, acc[rr][3]);
        }
      }
    }
    const float g2 = g_tp[m*4+2], g3 = g_tp[m*4+3];
#pragma unroll
    for (int rr=0;rr<4;rr++){
      const int r = r0+rr;
      const size_t e = (size_t)(e0+r);
      const float4 e4 = *(const float4*)(equiv + (e*32 + m)*4);
      const float4 n4 = *(const float4*)(envl + r*STH + 4*m);
      const float tpn0 = Xp[r*STX + 2*m];
      const float tpn1 = Xp[r*STX + 2*m+1];
      const float a2 = acc[rr][2]*inv_l[r*4+2]*g2;
      const float a3 = acc[rr][3]*inv_l[r*4+3]*g3;
      float4 o;
      o.x = c_old*e4.x + c_new*(acc[rr][0]*tpn0 + acc[rr][1]*tpn1);
      o.y = c_old*e4.y + c_new*(a2*(e4.x*n4.y) + a3*(e4.y*n4.x));
      o.z = c_old*e4.z + c_new*(a2*(e4.x*n4.z) + a3*(e4.z*n4.x));
      o.w = c_old*e4.w + c_new*(a2*(e4.x*n4.w) + a3*(e4.w*n4.x));
      *(float4*)(oute + e*128 + 4*m) = o;
    }
  }
}

extern "C" void kernel_launch(void* const* d_in, const int* in_sizes, int n_in,
                              void* d_out, int out_size, void* d_ws, size_t ws_size,
                              hipStream_t stream)
{
  const float* na   = (const float*)d_in[0];
  const float* ssi  = (const float*)d_in[1];
  const float* eqv  = (const float*)d_in[2];
  const float* cond = (const float*)d_in[3];
  const float* ruc  = (const float*)d_in[4];
  const float* W1   = (const float*)d_in[5];
  const float* b1   = (const float*)d_in[6];
  const float* W2   = (const float*)d_in[7];
  const float* Wq   = (const float*)d_in[8];
  const float* Wk   = (const float*)d_in[9];
  const float* ge   = (const float*)d_in[10];
  const float* gt   = (const float*)d_in[11];
  const float* Wp1  = (const float*)d_in[12];
  const float* bp1  = (const float*)d_in[13];
  const float* Wp2  = (const float*)d_in[14];
  const int*   esrc = (const int*)d_in[15];

  const int N = in_sizes[0] / 64;
  const int E = in_sizes[1] / 64;

  float* outs  = (float*)d_out;                // scalar_out [E,64]
  float* oute  = outs + (size_t)E*64;          // equiv_out [E,32,4]

  // CSR (no-atomics) path workspace requirement
  const size_t need = ((size_t)N*128 + (size_t)N*512 + (size_t)E*96) * sizeof(float)
                    + ((size_t)2*N + 1 + (size_t)E) * sizeof(int);

  if (ws_size >= need) {
    float* envn = (float*)d_ws;                  // N*128 (normalized env nodes)
    float* qn   = envn + (size_t)N*128;          // N*512
    float* elw  = qn   + (size_t)N*512;          // E*96: [el(32)|a0(32)|a1(32)] per edge
    int*   off  = (int*)(elw + (size_t)E*96);    // N+1 CSR offsets
    int*   cur  = off + (N + 1);                 // N (histogram, then scatter cursor)
    int*   perm = cur + N;                       // E sorted edge ids

    hipMemsetAsync(cur, 0, (size_t)N*sizeof(int), stream);
    k_qnode  <<<N/16, 256, 0, stream>>>(na, Wq, qn);
    k_hist   <<<(E+255)/256, 256, 0, stream>>>(esrc, E, cur);
    k_scan   <<<1, 1024, 0, stream>>>(cur, N, off);
    k_scatter<<<(E+255)/256, 256, 0, stream>>>(esrc, E, cur, perm);
    k_edge1  <<<E/32, 256, 0, stream>>>(ssi, cond, esrc, W1, b1, W2, Wk, qn, elw);
    k_env    <<<N, 128, 0, stream>>>(elw, eqv, perm, off, ge, envn);
    k_edge2  <<<E/32, 256, 0, stream>>>(ssi, cond, eqv, esrc, envn, gt, Wp1, bp1, Wp2, ruc, outs, oute);
  } else {
    // fallback: previous (verified) atomic path
    float* denom = (float*)d_ws;                 // N*32
    float* num   = denom + (size_t)N*32;         // N*128 (becomes env_nodes)
    float* qn    = num   + (size_t)N*128;        // N*512

    hipMemsetAsync(d_ws, 0, (size_t)N*160*sizeof(float), stream);
    k_qnode    <<<N/16, 256, 0, stream>>>(na, Wq, qn);
    k_edge1_atm<<<E/32, 256, 0, stream>>>(ssi, cond, eqv, esrc, W1, b1, W2, Wk, qn, denom, num);
    k_dnorm    <<<N, 128, 0, stream>>>(num, denom, ge);
    k_edge2    <<<E/32, 256, 0, stream>>>(ssi, cond, eqv, esrc, num, gt, Wp1, bp1, Wp2, ruc, outs, oute);
  }
}

// Round 2
// 1371.249 us; speedup vs baseline: 1.0162x; 1.0003x over previous
//
#include <hip/hip_runtime.h>
#include <math.h>

#define EPSF 1e-6f
#define STX 100   // row stride for X tiles (96 data cols, pad to 100: 16B-aligned, breaks pow2)
#define STH 132   // row stride for H tiles (128 data cols)

__device__ __forceinline__ float silu_f(float x){ return x * (1.0f/(1.0f + __expf(-x))); }

// ---------------- Qnode = node_attrs @ Wq : [N,64] x [64,512] ----------------
__global__ __launch_bounds__(256) void k_qnode(
    const float* __restrict__ na, const float* __restrict__ Wq,
    float* __restrict__ qn)
{
  __shared__ float At[64*16];
  const int nb = blockIdx.x * 16;
  const int t = threadIdx.x;
  for (int f = t; f < 16*64; f += 256){ int n = f>>6, i = f&63; At[i*16+n] = na[(size_t)(nb+n)*64 + i]; }
  __syncthreads();
  float acc0[16], acc1[16];
#pragma unroll
  for (int n=0;n<16;n++){ acc0[n]=0.f; acc1[n]=0.f; }
  for (int i=0;i<64;i++){
    float w0 = Wq[(size_t)i*512 + t];
    float w1 = Wq[(size_t)i*512 + t + 256];
#pragma unroll
    for (int n=0;n<16;n++){ float a = At[i*16+n]; acc0[n] = fmaf(a,w0,acc0[n]); acc1[n] = fmaf(a,w1,acc1[n]); }
  }
#pragma unroll
  for (int n=0;n<16;n++){
    qn[(size_t)(nb+n)*512 + t]       = acc0[n];
    qn[(size_t)(nb+n)*512 + t + 256] = acc1[n];
  }
}

// ================= CSR build: histogram -> exclusive scan -> scatter =================
__global__ __launch_bounds__(256) void k_hist(
    const int* __restrict__ esrc, int E, int* __restrict__ cnt)
{
  int i = blockIdx.x*256 + threadIdx.x;
  if (i < E) atomicAdd(cnt + esrc[i], 1);
}

// single-block exclusive scan; reads counts from cnt_cur, writes off[0..N] and
// rewrites cnt_cur[i] = off[i] (scatter cursor copy).
__global__ __launch_bounds__(1024) void k_scan(
    int* __restrict__ cnt_cur, int N, int* __restrict__ off)
{
  __shared__ int part[1024];
  const int t = threadIdx.x;
  const int ipt = (N + 1023) >> 10;
  int s = 0;
  for (int k=0;k<ipt;k++){ int i = t*ipt + k; if (i < N) s += cnt_cur[i]; }
  part[t] = s;
  __syncthreads();
  for (int d=1; d<1024; d<<=1){
    int v = (t >= d) ? part[t-d] : 0;
    __syncthreads();
    part[t] += v;
    __syncthreads();
  }
  int run = (t==0) ? 0 : part[t-1];
  for (int k=0;k<ipt;k++){
    int i = t*ipt + k;
    if (i < N){ int c = cnt_cur[i]; off[i] = run; cnt_cur[i] = run; run += c; }
  }
  if (t == 1023) off[N] = part[1023];
}

__global__ __launch_bounds__(256) void k_scatter(
    const int* __restrict__ esrc, int E, int* __restrict__ cur,
    int* __restrict__ perm, int* __restrict__ ssrc)
{
  int i = blockIdx.x*256 + threadIdx.x;
  if (i < E){ int s = esrc[i]; int p = atomicAdd(cur + s, 1); perm[p] = i; ssrc[p] = s; }
}

// ---------------- edge kernel 1 (sorted CSR order): env-MLP + K-proj + logits ----------------
// Block handles sorted slots e0..e0+31 (edge ids perm[slot]); sorted blocks share src nodes
// -> the qn gather is L1/L2-resident. elw written at the SORTED slot (k_env reads it linearly).
__global__ __launch_bounds__(256,4) void k_edge1(
    const float* __restrict__ ssi, const float* __restrict__ cond,
    const int* __restrict__ perm, const int* __restrict__ ssrc,
    const float* __restrict__ W1, const float* __restrict__ b1,
    const float* __restrict__ W2, const float* __restrict__ Wk,
    const float* __restrict__ qn,
    float* __restrict__ elw)
{
  __shared__ float Xs[32*STX];   // 12.8 KB  [r][ s(64) | cond(32) ]
  __shared__ float Hs[32*STH];   // 16.9 KB
  __shared__ float lg[32*32];    // 4 KB
  __shared__ int src_l[32];
  __shared__ int perm_l[32];     // total ~33.2 KB -> 4 blocks/CU
  const int e0 = blockIdx.x * 32;
  const int t = threadIdx.x;
  const int r0 = (t>>5)*4;

  if (t < 32){ src_l[t] = ssrc[e0+t]; perm_l[t] = perm[e0+t]; }
  __syncthreads();
  for (int f=t; f<512; f+=256){ int r=f>>4, q=(f&15)*4;
    *(float4*)(Xs + r*STX + q) = *(const float4*)(ssi + (size_t)perm_l[r]*64 + q); }
  { int f=t; int r=f>>3, q=(f&7)*4;
    *(float4*)(Xs + r*STX + 64 + q) = *(const float4*)(cond + (size_t)perm_l[r]*32 + q); }
  __syncthreads();

  // H = silu(X @ W_env1 + b_env1)
  {
    const int c0 = (t&31)*4;
    float acc[4][4] = {};
    for (int i0=0;i0<96;i0+=4){
      float4 wv[4], xv[4];
#pragma unroll
      for (int k=0;k<4;k++) wv[k] = *(const float4*)(W1 + (size_t)(i0+k)*128 + c0);
#pragma unroll
      for (int rr=0;rr<4;rr++) xv[rr] = *(const float4*)(Xs + (r0+rr)*STX + i0);
#pragma unroll
      for (int rr=0;rr<4;rr++){
        const float xs[4] = {xv[rr].x,xv[rr].y,xv[rr].z,xv[rr].w};
#pragma unroll
        for (int k=0;k<4;k++){
          acc[rr][0] = fmaf(xs[k], wv[k].x, acc[rr][0]);
          acc[rr][1] = fmaf(xs[k], wv[k].y, acc[rr][1]);
          acc[rr][2] = fmaf(xs[k], wv[k].z, acc[rr][2]);
          acc[rr][3] = fmaf(xs[k], wv[k].w, acc[rr][3]);
        }
      }
    }
    const float4 bb = *(const float4*)(b1 + c0);
#pragma unroll
    for (int rr=0;rr<4;rr++){
      float4 h;
      h.x = silu_f(acc[rr][0]+bb.x); h.y = silu_f(acc[rr][1]+bb.y);
      h.z = silu_f(acc[rr][2]+bb.z); h.w = silu_f(acc[rr][3]+bb.w);
      *(float4*)(Hs + (r0+rr)*STH + c0) = h;
    }
  }
  __syncthreads();

  // w = H @ W_env2 (regs), then park in wl (aliases Hs after barrier)
  float wacc[4][2] = {};
  {
    const int c0 = (t&31)*2;
    for (int j0=0;j0<128;j0+=4){
      float2 w2[4]; float4 hv[4];
#pragma unroll
      for (int k=0;k<4;k++) w2[k] = *(const float2*)(W2 + (size_t)(j0+k)*64 + c0);
#pragma unroll
      for (int rr=0;rr<4;rr++) hv[rr] = *(const float4*)(Hs + (r0+rr)*STH + j0);
#pragma unroll
      for (int rr=0;rr<4;rr++){
        const float hs[4] = {hv[rr].x,hv[rr].y,hv[rr].z,hv[rr].w};
#pragma unroll
        for (int k=0;k<4;k++){
          wacc[rr][0] = fmaf(hs[k], w2[k].x, wacc[rr][0]);
          wacc[rr][1] = fmaf(hs[k], w2[k].y, wacc[rr][1]);
        }
      }
    }
  }
  __syncthreads();
  float* wl = Hs;  // 32 x 66 row-major
  {
    const int c0 = (t&31)*2;
#pragma unroll
    for (int rr=0;rr<4;rr++)
      *(float2*)(wl + (r0+rr)*66 + c0) = make_float2(wacc[rr][0], wacc[rr][1]);
  }

  // K = s @ Wk ; logits[r][m] = K . Q[src]  (src repeated within sorted block -> cached)
  for (int it=0; it<4; it++){
    const int c0k = (t&31)*4 + it*128;
    float acc[4][4] = {};
    for (int i0=0;i0<64;i0+=4){
      float4 wv[4], xv[4];
#pragma unroll
      for (int k=0;k<4;k++) wv[k] = *(const float4*)(Wk + (size_t)(i0+k)*512 + c0k);
#pragma unroll
      for (int rr=0;rr<4;rr++) xv[rr] = *(const float4*)(Xs + (r0+rr)*STX + i0);
#pragma unroll
      for (int rr=0;rr<4;rr++){
        const float xs[4] = {xv[rr].x,xv[rr].y,xv[rr].z,xv[rr].w};
#pragma unroll
        for (int k=0;k<4;k++){
          acc[rr][0] = fmaf(xs[k], wv[k].x, acc[rr][0]);
          acc[rr][1] = fmaf(xs[k], wv[k].y, acc[rr][1]);
          acc[rr][2] = fmaf(xs[k], wv[k].z, acc[rr][2]);
          acc[rr][3] = fmaf(xs[k], wv[k].w, acc[rr][3]);
        }
      }
    }
    const int m = ((t&31)>>2) + it*8;
#pragma unroll
    for (int rr=0;rr<4;rr++){
      const float4 q = *(const float4*)(qn + (size_t)src_l[r0+rr]*512 + c0k);
      float p = acc[rr][0]*q.x + acc[rr][1]*q.y + acc[rr][2]*q.z + acc[rr][3]*q.w;
      p += __shfl_xor(p, 1);
      p += __shfl_xor(p, 2);
      if ((t&3)==0) lg[(r0+rr)*32 + m] = p;
    }
  }
  __syncthreads();

  // exp(clip(logits*INV_SQRTD)); stream (el, el*w0, el*w1) at SORTED slot. No atomics.
  for (int f=t; f<1024; f+=256){
    int r=f>>5, m=f&31;
    float l = lg[f] * 0.25f;
    l = fminf(5.0f, fmaxf(-5.0f, l));
    const float el = __expf(l);
    const size_t b = (size_t)(e0+r)*96;
    elw[b + m]      = el;
    elw[b + 32 + m] = el * wl[r*66 + 2*m];
    elw[b + 64 + m] = el * wl[r*66 + 2*m+1];
  }
}

// ---------------- per-node: CSR segment-sum + attn division + env SO(3) layernorm ----------------
// One block per node; thread t = 4*m + c. elw is in sorted order -> contiguous stream.
__global__ __launch_bounds__(128) void k_env(
    const float* __restrict__ elw, const float* __restrict__ equiv,
    const int* __restrict__ perm, const int* __restrict__ off,
    const float* __restrict__ g_env, float* __restrict__ envn)
{
  __shared__ float red[128];
  __shared__ float inv0s, inv1s;
  const int n = blockIdx.x, t = threadIdx.x;
  const int m = t>>2, c = t&3;
  const int j0 = off[n], j1 = off[n+1];
  float den = 0.f, acc = 0.f;
  for (int j=j0; j<j1; j++){
    const size_t b = (size_t)j*96;                        // contiguous in j now
    const float el = elw[b + m];
    const float a  = elw[b + (c ? 64 : 32) + m];
    const int pe = perm[j];                               // uniform -> scalar load
    const float ev = equiv[((size_t)pe*32 + m)*4 + c];    // 512B coalesced per row
    den += el;
    acc = fmaf(a, ev, acc);
  }
  const float x = (den > 0.f) ? acc/den : 0.f;
  red[t] = x*x;
  __syncthreads();
  if (t < 32){
    float p0 = red[4*t];
    float p1 = red[4*t+1]+red[4*t+2]+red[4*t+3];
#pragma unroll
    for (int k=1;k<32;k<<=1){ p0 += __shfl_xor(p0,k); p1 += __shfl_xor(p1,k); }
    if (t==0){ inv0s = 1.0f/sqrtf(p0*(1.0f/32.0f) + EPSF); inv1s = 1.0f/sqrtf(p1*(1.0f/96.0f) + EPSF); }
  }
  __syncthreads();
  const float g = g_env[m*2 + (c?1:0)];
  envn[(size_t)n*128 + t] = x * (c ? inv1s : inv0s) * g;
}

// ================= fallback path (atomic reduction), used only if ws too small =================
__global__ __launch_bounds__(256,4) void k_edge1_atm(
    const float* __restrict__ ssi, const float* __restrict__ cond,
    const float* __restrict__ equiv, const int* __restrict__ esrc,
    const float* __restrict__ W1, const float* __restrict__ b1,
    const float* __restrict__ W2, const float* __restrict__ Wk,
    const float* __restrict__ qn,
    float* __restrict__ denom, float* __restrict__ num)
{
  __shared__ float Xs[32*STX];
  __shared__ float Hs[32*STH];
  __shared__ float lg[32*32];
  __shared__ int src_l[32];
  const int e0 = blockIdx.x * 32;
  const int t = threadIdx.x;
  const int r0 = (t>>5)*4;

  if (t < 32) src_l[t] = esrc[e0+t];
  for (int f=t; f<512; f+=256){ int r=f>>4, q=(f&15)*4;
    *(float4*)(Xs + r*STX + q) = *(const float4*)(ssi + (size_t)(e0+r)*64 + q); }
  { int f=t; int r=f>>3, q=(f&7)*4;
    *(float4*)(Xs + r*STX + 64 + q) = *(const float4*)(cond + (size_t)(e0+r)*32 + q); }
  __syncthreads();

  {
    const int c0 = (t&31)*4;
    float acc[4][4] = {};
    for (int i0=0;i0<96;i0+=4){
      float4 wv[4], xv[4];
#pragma unroll
      for (int k=0;k<4;k++) wv[k] = *(const float4*)(W1 + (size_t)(i0+k)*128 + c0);
#pragma unroll
      for (int rr=0;rr<4;rr++) xv[rr] = *(const float4*)(Xs + (r0+rr)*STX + i0);
#pragma unroll
      for (int rr=0;rr<4;rr++){
        const float xs[4] = {xv[rr].x,xv[rr].y,xv[rr].z,xv[rr].w};
#pragma unroll
        for (int k=0;k<4;k++){
          acc[rr][0] = fmaf(xs[k], wv[k].x, acc[rr][0]);
          acc[rr][1] = fmaf(xs[k], wv[k].y, acc[rr][1]);
          acc[rr][2] = fmaf(xs[k], wv[k].z, acc[rr][2]);
          acc[rr][3] = fmaf(xs[k], wv[k].w, acc[rr][3]);
        }
      }
    }
    const float4 bb = *(const float4*)(b1 + c0);
#pragma unroll
    for (int rr=0;rr<4;rr++){
      float4 h;
      h.x = silu_f(acc[rr][0]+bb.x); h.y = silu_f(acc[rr][1]+bb.y);
      h.z = silu_f(acc[rr][2]+bb.z); h.w = silu_f(acc[rr][3]+bb.w);
      *(float4*)(Hs + (r0+rr)*STH + c0) = h;
    }
  }
  __syncthreads();

  float wacc[4][2] = {};
  {
    const int c0 = (t&31)*2;
    for (int j0=0;j0<128;j0+=4){
      float2 w2[4]; float4 hv[4];
#pragma unroll
      for (int k=0;k<4;k++) w2[k] = *(const float2*)(W2 + (size_t)(j0+k)*64 + c0);
#pragma unroll
      for (int rr=0;rr<4;rr++) hv[rr] = *(const float4*)(Hs + (r0+rr)*STH + j0);
#pragma unroll
      for (int rr=0;rr<4;rr++){
        const float hs[4] = {hv[rr].x,hv[rr].y,hv[rr].z,hv[rr].w};
#pragma unroll
        for (int k=0;k<4;k++){
          wacc[rr][0] = fmaf(hs[k], w2[k].x, wacc[rr][0]);
          wacc[rr][1] = fmaf(hs[k], w2[k].y, wacc[rr][1]);
        }
      }
    }
  }
  __syncthreads();
  float* wl = Hs;
  {
    const int c0 = (t&31)*2;
#pragma unroll
    for (int rr=0;rr<4;rr++)
      *(float2*)(wl + (r0+rr)*66 + c0) = make_float2(wacc[rr][0], wacc[rr][1]);
  }

  for (int it=0; it<4; it++){
    const int c0k = (t&31)*4 + it*128;
    float acc[4][4] = {};
    for (int i0=0;i0<64;i0+=4){
      float4 wv[4], xv[4];
#pragma unroll
      for (int k=0;k<4;k++) wv[k] = *(const float4*)(Wk + (size_t)(i0+k)*512 + c0k);
#pragma unroll
      for (int rr=0;rr<4;rr++) xv[rr] = *(const float4*)(Xs + (r0+rr)*STX + i0);
#pragma unroll
      for (int rr=0;rr<4;rr++){
        const float xs[4] = {xv[rr].x,xv[rr].y,xv[rr].z,xv[rr].w};
#pragma unroll
        for (int k=0;k<4;k++){
          acc[rr][0] = fmaf(xs[k], wv[k].x, acc[rr][0]);
          acc[rr][1] = fmaf(xs[k], wv[k].y, acc[rr][1]);
          acc[rr][2] = fmaf(xs[k], wv[k].z, acc[rr][2]);
          acc[rr][3] = fmaf(xs[k], wv[k].w, acc[rr][3]);
        }
      }
    }
    const int m = ((t&31)>>2) + it*8;
#pragma unroll
    for (int rr=0;rr<4;rr++){
      const float4 q = *(const float4*)(qn + (size_t)src_l[r0+rr]*512 + c0k);
      float p = acc[rr][0]*q.x + acc[rr][1]*q.y + acc[rr][2]*q.z + acc[rr][3]*q.w;
      p += __shfl_xor(p, 1);
      p += __shfl_xor(p, 2);
      if ((t&3)==0) lg[(r0+rr)*32 + m] = p;
    }
  }
  __syncthreads();

  for (int f=t; f<1024; f+=256){
    int r=f>>5, m=f&31;
    float l = lg[f] * 0.25f;
    l = fminf(5.0f, fmaxf(-5.0f, l));
    float el = __expf(l);
    lg[f] = el;
    atomicAdd(denom + (size_t)src_l[r]*32 + m, el);
  }
  __syncthreads();

  for (int f=t; f<1024; f+=256){
    int r=f>>5, m=f&31;
    const float el = lg[r*32+m];
    const float w0 = wl[r*66 + 2*m]   * el;
    const float w1 = wl[r*66 + 2*m+1] * el;
    const float4 ev = *(const float4*)(equiv + ((size_t)(e0+r)*32 + m)*4);
    float* np = num + (size_t)src_l[r]*128 + 4*m;
    atomicAdd(np+0, w0*ev.x);
    atomicAdd(np+1, w1*ev.y);
    atomicAdd(np+2, w1*ev.z);
    atomicAdd(np+3, w1*ev.w);
  }
}

__global__ __launch_bounds__(128) void k_dnorm(
    float* __restrict__ num, const float* __restrict__ denom,
    const float* __restrict__ g_env)
{
  __shared__ float red[128];
  __shared__ float inv0s, inv1s;
  const int n = blockIdx.x, t = threadIdx.x;
  const int m = t>>2, c = t&3;
  const float d = denom[(size_t)n*32+m];
  const float x = (d > 0.0f) ? num[(size_t)n*128+t]/d : 0.0f;
  red[t] = x*x;
  __syncthreads();
  if (t < 32){
    float p0 = red[4*t];
    float p1 = red[4*t+1]+red[4*t+2]+red[4*t+3];
#pragma unroll
    for (int k=1;k<32;k<<=1){ p0 += __shfl_xor(p0,k); p1 += __shfl_xor(p1,k); }
    if (t==0){ inv0s = 1.0f/sqrtf(p0*(1.0f/32.0f) + EPSF); inv1s = 1.0f/sqrtf(p1*(1.0f/96.0f) + EPSF); }
  }
  __syncthreads();
  const float g = g_env[m*2 + (c?1:0)];
  num[(size_t)n*128+t] = x * (c ? inv1s : inv0s) * g;
}

// ---------------- edge kernel 2: gather env, tp + norms, p-MLP, outputs ----------------
// Sorted order when eord!=nullptr (eord[slot] = edge id; esorted srcs in nsrc[slot]);
// identity order when eord==nullptr (nsrc = esrc indexed at slot).
__global__ __launch_bounds__(256,3) void k_edge2(
    const float* __restrict__ ssi, const float* __restrict__ cond,
    const float* __restrict__ equiv, const int* __restrict__ nsrc,
    const int* __restrict__ eord,
    const float* __restrict__ envn, const float* __restrict__ g_tp,
    const float* __restrict__ Wp1, const float* __restrict__ bp1,
    const float* __restrict__ Wp2, const float* __restrict__ ruc,
    float* __restrict__ outs, float* __restrict__ oute)
{
  __shared__ float envl[32*STH];   // 16.9 KB gathered env rows (stride 132 kills 16-bank aliasing)
  __shared__ float Xp[32*STX];     // 12.8 KB [r][ tpn(64) | cond(32) ]
  __shared__ float Hp[32*STH];     // 16.9 KB
  __shared__ float inv_l[32*4];
  __shared__ int src_l[32];
  __shared__ int perm_l[32];       // total ~47 KB -> 3 blocks/CU
  const int e0 = blockIdx.x * 32;
  const int t = threadIdx.x;
  const int r0 = (t>>5)*4;
  if (t < 32){
    src_l[t]  = nsrc[e0+t];
    perm_l[t] = eord ? eord[e0+t] : (e0+t);
  }
  __syncthreads();
  for (int f=t; f<1024; f+=256){ int r=f>>5, q=(f&31)*4;
    *(float4*)(envl + r*STH + q) = *(const float4*)(envn + (size_t)src_l[r]*128 + q); }
  { int f=t; int r=f>>3, q=(f&7)*4;
    *(float4*)(Xp + r*STX + 64 + q) = *(const float4*)(cond + (size_t)perm_l[r]*32 + q); }
  __syncthreads();

  // 4 per-edge RMS norms of the tensor product (tp never materialized)
  {
    const int r = t>>3, sub = t&7;
    const size_t pe = (size_t)perm_l[r];
    float ss0=0,ss1=0,ss2=0,ss3=0;
#pragma unroll
    for (int mm=0;mm<4;mm++){
      const int m = sub*4+mm;
      const float4 e4 = *(const float4*)(equiv + (pe*32 + m)*4);
      const float4 n4 = *(const float4*)(envl + r*STH + 4*m);
      const float tp0 = e4.x*n4.x;
      const float dv  = e4.y*n4.y + e4.z*n4.z + e4.w*n4.w;
      const float tp1 = dv*0.5773502691896258f;
      ss0 += tp0*tp0;
      ss1 += tp1*tp1;
      ss2 += e4.x*e4.x*(n4.y*n4.y + n4.z*n4.z + n4.w*n4.w);
      ss3 += n4.x*n4.x*(e4.y*e4.y + e4.z*e4.z + e4.w*e4.w);
    }
#pragma unroll
    for (int k=1;k<8;k<<=1){
      ss0 += __shfl_xor(ss0,k); ss1 += __shfl_xor(ss1,k);
      ss2 += __shfl_xor(ss2,k); ss3 += __shfl_xor(ss3,k);
    }
    if (sub == 0){
      inv_l[r*4+0] = 1.0f/sqrtf(ss0*(1.0f/32.0f) + EPSF);
      inv_l[r*4+1] = 1.0f/sqrtf(ss1*(1.0f/32.0f) + EPSF);
      inv_l[r*4+2] = 1.0f/sqrtf(ss2*(1.0f/96.0f) + EPSF);
      inv_l[r*4+3] = 1.0f/sqrtf(ss3*(1.0f/96.0f) + EPSF);
    }
  }
  __syncthreads();

  // Xp scalar cols: xp[2m]=tpn0, xp[2m+1]=tpn1
  for (int f=t; f<2048; f+=256){
    const int r = f>>6, col = f&63, m = col>>1;
    const float4 e4 = *(const float4*)(equiv + ((size_t)perm_l[r]*32 + m)*4);
    const float4 n4 = *(const float4*)(envl + r*STH + 4*m);
    float v;
    if (col & 1)
      v = (e4.y*n4.y + e4.z*n4.z + e4.w*n4.w)*0.5773502691896258f * inv_l[r*4+1] * g_tp[m*4+1];
    else
      v = e4.x*n4.x * inv_l[r*4+0] * g_tp[m*4+0];
    Xp[r*STX + col] = v;
  }
  __syncthreads();

  // Hp = silu(Xp @ Wp1 + bp1)
  {
    const int c0 = (t&31)*4;
    float acc[4][4] = {};
    for (int i0=0;i0<96;i0+=4){
      float4 wv[4], xv[4];
#pragma unroll
      for (int k=0;k<4;k++) wv[k] = *(const float4*)(Wp1 + (size_t)(i0+k)*128 + c0);
#pragma unroll
      for (int rr=0;rr<4;rr++) xv[rr] = *(const float4*)(Xp + (r0+rr)*STX + i0);
#pragma unroll
      for (int rr=0;rr<4;rr++){
        const float xs[4] = {xv[rr].x,xv[rr].y,xv[rr].z,xv[rr].w};
#pragma unroll
        for (int k=0;k<4;k++){
          acc[rr][0] = fmaf(xs[k], wv[k].x, acc[rr][0]);
          acc[rr][1] = fmaf(xs[k], wv[k].y, acc[rr][1]);
          acc[rr][2] = fmaf(xs[k], wv[k].z, acc[rr][2]);
          acc[rr][3] = fmaf(xs[k], wv[k].w, acc[rr][3]);
        }
      }
    }
    const float4 bb = *(const float4*)(bp1 + c0);
#pragma unroll
    for (int rr=0;rr<4;rr++){
      float4 h;
      h.x = silu_f(acc[rr][0]+bb.x); h.y = silu_f(acc[rr][1]+bb.y);
      h.z = silu_f(acc[rr][2]+bb.z); h.w = silu_f(acc[rr][3]+bb.w);
      *(float4*)(Hp + (r0+rr)*STH + c0) = h;
    }
  }
  __syncthreads();

  const float rv = ruc[0];
  const float c_old = 1.0f/sqrtf(rv*rv + 1.0f);
  const float c_new = rv * c_old;

  // op[:, :64] = new_scalar -> scalar_out with residual
  {
    const int c0 = (t&31)*2;
    float acc[4][2] = {};
    for (int j0=0;j0<128;j0+=4){
      float2 w2[4]; float4 hv[4];
#pragma unroll
      for (int k=0;k<4;k++) w2[k] = *(const float2*)(Wp2 + (size_t)(j0+k)*192 + c0);
#pragma unroll
      for (int rr=0;rr<4;rr++) hv[rr] = *(const float4*)(Hp + (r0+rr)*STH + j0);
#pragma unroll
      for (int rr=0;rr<4;rr++){
        const float hs[4] = {hv[rr].x,hv[rr].y,hv[rr].z,hv[rr].w};
#pragma unroll
        for (int k=0;k<4;k++){
          acc[rr][0] = fmaf(hs[k], w2[k].x, acc[rr][0]);
          acc[rr][1] = fmaf(hs[k], w2[k].y, acc[rr][1]);
        }
      }
    }
#pragma unroll
    for (int rr=0;rr<4;rr++){
      const size_t e = (size_t)perm_l[r0+rr];
      const float2 s2 = *(const float2*)(ssi + e*64 + c0);
      float2 o2; o2.x = c_old*s2.x + c_new*acc[rr][0]; o2.y = c_old*s2.y + c_new*acc[rr][1];
      *(float2*)(outs + e*64 + c0) = o2;
    }
  }

  // op[:, 64:] = pw[m][0..3] -> equiv_out with residual (thread owns mul m = t&31)
  {
    const int m = t&31;
    float acc[4][4] = {};
    for (int j0=0;j0<128;j0+=4){
      float4 w4[4]; float4 hv[4];
#pragma unroll
      for (int k=0;k<4;k++) w4[k] = *(const float4*)(Wp2 + (size_t)(j0+k)*192 + 64 + 4*m);
#pragma unroll
      for (int rr=0;rr<4;rr++) hv[rr] = *(const float4*)(Hp + (r0+rr)*STH + j0);
#pragma unroll
      for (int rr=0;rr<4;rr++){
        const float hs[4] = {hv[rr].x,hv[rr].y,hv[rr].z,hv[rr].w};
#pragma unroll
        for (int k=0;k<4;k++){
          acc[rr][0] = fmaf(hs[k], w4[k].x, acc[rr][0]);
          acc[rr][1] = fmaf(hs[k], w4[k].y, acc[rr][1]);
          acc[rr][2] = fmaf(hs[k], w4[k].z, acc[rr][2]);
          acc[rr][3] = fmaf(hs[k], w4[k].w, acc[rr][3]);
        }
      }
    }
    const float g2 = g_tp[m*4+2], g3 = g_tp[m*4+3];
#pragma unroll
    for (int rr=0;rr<4;rr++){
      const int r = r0+rr;
      const size_t e = (size_t)perm_l[r];
      const float4 e4 = *(const float4*)(equiv + (e*32 + m)*4);
      const float4 n4 = *(const float4*)(envl + r*STH + 4*m);
      const float tpn0 = Xp[r*STX + 2*m];
      const float tpn1 = Xp[r*STX + 2*m+1];
      const float a2 = acc[rr][2]*inv_l[r*4+2]*g2;
      const float a3 = acc[rr][3]*inv_l[r*4+3]*g3;
      float4 o;
      o.x = c_old*e4.x + c_new*(acc[rr][0]*tpn0 + acc[rr][1]*tpn1);
      o.y = c_old*e4.y + c_new*(a2*(e4.x*n4.y) + a3*(e4.y*n4.x));
      o.z = c_old*e4.z + c_new*(a2*(e4.x*n4.z) + a3*(e4.z*n4.x));
      o.w = c_old*e4.w + c_new*(a2*(e4.x*n4.w) + a3*(e4.w*n4.x));
      *(float4*)(oute + e*128 + 4*m) = o;
    }
  }
}

extern "C" void kernel_launch(void* const* d_in, const int* in_sizes, int n_in,
                              void* d_out, int out_size, void* d_ws, size_t ws_size,
                              hipStream_t stream)
{
  const float* na   = (const float*)d_in[0];
  const float* ssi  = (const float*)d_in[1];
  const float* eqv  = (const float*)d_in[2];
  const float* cond = (const float*)d_in[3];
  const float* ruc  = (const float*)d_in[4];
  const float* W1   = (const float*)d_in[5];
  const float* b1   = (const float*)d_in[6];
  const float* W2   = (const float*)d_in[7];
  const float* Wq   = (const float*)d_in[8];
  const float* Wk   = (const float*)d_in[9];
  const float* ge   = (const float*)d_in[10];
  const float* gt   = (const float*)d_in[11];
  const float* Wp1  = (const float*)d_in[12];
  const float* bp1  = (const float*)d_in[13];
  const float* Wp2  = (const float*)d_in[14];
  const int*   esrc = (const int*)d_in[15];

  const int N = in_sizes[0] / 64;
  const int E = in_sizes[1] / 64;

  float* outs  = (float*)d_out;                // scalar_out [E,64]
  float* oute  = outs + (size_t)E*64;          // equiv_out [E,32,4]

  // CSR (no-atomics, sorted) path workspace requirement
  const size_t need = ((size_t)N*128 + (size_t)N*512 + (size_t)E*96) * sizeof(float)
                    + ((size_t)2*N + 1 + (size_t)2*E) * sizeof(int);

  if (ws_size >= need) {
    float* envn = (float*)d_ws;                  // N*128 (normalized env nodes)
    float* qn   = envn + (size_t)N*128;          // N*512
    float* elw  = qn   + (size_t)N*512;          // E*96: [el(32)|a0(32)|a1(32)] per SORTED slot
    int*   off  = (int*)(elw + (size_t)E*96);    // N+1 CSR offsets
    int*   cur  = off + (N + 1);                 // N (histogram, then scatter cursor)
    int*   perm = cur + N;                       // E sorted edge ids
    int*   ssrc = perm + E;                      // E sorted srcs

    hipMemsetAsync(cur, 0, (size_t)N*sizeof(int), stream);
    k_qnode  <<<N/16, 256, 0, stream>>>(na, Wq, qn);
    k_hist   <<<(E+255)/256, 256, 0, stream>>>(esrc, E, cur);
    k_scan   <<<1, 1024, 0, stream>>>(cur, N, off);
    k_scatter<<<(E+255)/256, 256, 0, stream>>>(esrc, E, cur, perm, ssrc);
    k_edge1  <<<E/32, 256, 0, stream>>>(ssi, cond, perm, ssrc, W1, b1, W2, Wk, qn, elw);
    k_env    <<<N, 128, 0, stream>>>(elw, eqv, perm, off, ge, envn);
    k_edge2  <<<E/32, 256, 0, stream>>>(ssi, cond, eqv, ssrc, perm, envn, gt, Wp1, bp1, Wp2, ruc, outs, oute);
  } else {
    // fallback: atomic path, identity edge order
    float* denom = (float*)d_ws;                 // N*32
    float* num   = denom + (size_t)N*32;         // N*128 (becomes env_nodes)
    float* qn    = num   + (size_t)N*128;        // N*512

    hipMemsetAsync(d_ws, 0, (size_t)N*160*sizeof(float), stream);
    k_qnode    <<<N/16, 256, 0, stream>>>(na, Wq, qn);
    k_edge1_atm<<<E/32, 256, 0, stream>>>(ssi, cond, eqv, esrc, W1, b1, W2, Wk, qn, denom, num);
    k_dnorm    <<<N, 128, 0, stream>>>(num, denom, ge);
    k_edge2    <<<E/32, 256, 0, stream>>>(ssi, cond, eqv, esrc, (const int*)nullptr, num, gt, Wp1, bp1, Wp2, ruc, outs, oute);
  }
}